// Round 3
// baseline (177.359 us; speedup 1.0000x reference)
//
#include <hip/hip_runtime.h>
#include <hip/hip_bf16.h>

typedef __attribute__((ext_vector_type(8))) short short8;
typedef __attribute__((ext_vector_type(4))) float floatx4;

#define MARGIN 0.3f
static constexpr int N = 8192;   // b*n points
static constexpr int C = 256;    // feature dim

// async 16B global->LDS (dest = wave-uniform base + lane*16)
__device__ __forceinline__ void async16(const void* g, void* l) {
    __builtin_amdgcn_global_load_lds(
        (const __attribute__((address_space(1))) unsigned int*)g,
        (__attribute__((address_space(3))) unsigned int*)l, 16, 0, 0);
}

// ---------------- kernel 0: fp32->bf16 convert + row norms + init --------------
// blocks [0, N/4): one wave per row (4 rows / 256-thr block)
// blocks [N/4, N/4+64): fused mse + dr partial reductions -> scalars[1+b]
__global__ void k_prep_sq(const float* __restrict__ feat, __hip_bfloat16* __restrict__ fb,
                          float* __restrict__ sq, unsigned* __restrict__ posmax,
                          unsigned* __restrict__ negmin,
                          const float* __restrict__ s0, const float* __restrict__ s1,
                          const float* __restrict__ s2, const float* __restrict__ gt,
                          const float* __restrict__ e0, const float* __restrict__ e1,
                          const float* __restrict__ l0, const float* __restrict__ l1,
                          float* __restrict__ scalars, unsigned* __restrict__ done) {
    if (blockIdx.x >= N / 4) {
        const int E = 64 * 1024;
        int bid = blockIdx.x - N / 4;
        if (bid == 0 && threadIdx.x == 0) *done = 0u;
        int tid = bid * 256 + threadIdx.x;
        int nth = 64 * 256;
        float acc = 0.f;
        for (int i = tid; i < E; i += nth) acc += fabsf(e0[i] - l0[i]) * (1.f / E);
        for (int i = tid; i < E; i += nth) acc += fabsf(e1[i] - l1[i]) * (1.f / E);
        if (tid < 192) {
            int k = tid >> 6, i = tid & 63;
            const float* s = (k == 0) ? s0 : ((k == 1) ? s1 : s2);
            float d = s[i] - gt[i];
            acc += d * d * (1.f / 192.f);
        }
#pragma unroll
        for (int off = 32; off; off >>= 1) acc += __shfl_xor(acc, off);
        __shared__ float red[4];
        int lane = threadIdx.x & 63, wv = threadIdx.x >> 6;
        if (lane == 0) red[wv] = acc;
        __syncthreads();
        if (threadIdx.x == 0)
            scalars[1 + bid] = red[0] + red[1] + red[2] + red[3];
        return;
    }
    int row = blockIdx.x * 4 + (threadIdx.x >> 6);
    int lane = threadIdx.x & 63;
    float4 v = ((const float4*)feat)[row * 64 + lane];
    union { __hip_bfloat16 h[4]; ushort4 u; } cv;
    cv.h[0] = __float2bfloat16(v.x); cv.h[1] = __float2bfloat16(v.y);
    cv.h[2] = __float2bfloat16(v.z); cv.h[3] = __float2bfloat16(v.w);
    ((ushort4*)fb)[row * 64 + lane] = cv.u;
    float s = v.x * v.x + v.y * v.y + v.z * v.z + v.w * v.w;
#pragma unroll
    for (int off = 32; off; off >>= 1) s += __shfl_xor(s, off);
    if (lane == 0) {
        sq[row] = s;
        posmax[row] = 0u;
        negmin[row] = 0x7f800000u;   // +inf
    }
}

// ---------------- kernel 1: SYMMETRIC pairwise mining via bf16 MFMA ------------
// Upper-triangle 128x128 tile-pairs only (I<=J): 2080 of 4096, mapped FLAT over
// 512 blocks (4-5 tiles each; consecutive tiles share the A-strip). Each tile
// is mined both ways (rows -> negmin[i] in registers; cols -> negmin[j] via
// quad-shfl + atomicMin per phase). All per-thread mining state is in
// statically-indexed ext-vectors (floatx4) so nothing gets promoted to LDS.
// Last block (done-counter ticket) performs the final combine.
__global__ __launch_bounds__(256, 2)
void k_trip(const __hip_bfloat16* __restrict__ fb, const float* __restrict__ sq,
            unsigned* __restrict__ posmax, unsigned* __restrict__ negmin,
            const float* __restrict__ scalars, unsigned* __restrict__ done,
            float* __restrict__ out) {
    __shared__ uint4 Bs[2][2048];   // 2 x 32 KB = 64 KB
    __shared__ unsigned sTicket;
    __shared__ float fred[4];

    const int t = threadIdx.x;
    const int w = t >> 6, lane = t & 63;
    const int wi = w >> 1, wj = w & 1;
    const int quad = lane >> 4, l15 = lane & 15;

    // ---- flat triangular tile range: tiles [(bid*65)>>4, ((bid+1)*65)>>4) ----
    const int bid = blockIdx.x;
    int tt = (bid * 65) >> 4;
    const int tend = ((bid + 1) * 65) >> 4;
    int I = 0, base = 0;
    while (base + 64 - I <= tt) { base += 64 - I; ++I; }   // strip I: [base, base+64-I)
    int J = I + (tt - base);

    // ---- hoisted staging offsets (bf16-element units) ----
    int soff[8];
#pragma unroll
    for (int it = 0; it < 8; ++it) {
        int s = it * 256 + t;
        int srow = s >> 5, sg = s & 31;
        soff[it] = srow * C + (sg ^ (srow & 7)) * 8;
    }

    // ---- per-A-segment state (ALL statically indexed -> VGPRs) ----
    short8 a[4][8];
    floatx4 si[4];                // sq of this lane's acc rows, si[ti][r]
    floatx4 nm[4];                // row-mining running min (m = sj - 2*dot)
    float pm[2];                  // row-side positive max (diag tiles)
    int ib = 0;
#pragma unroll
    for (int q = 0; q < 4; ++q) nm[q] = (floatx4){INFINITY, INFINITY, INFINITY, INFINITY};
    pm[0] = -INFINITY; pm[1] = -INFINITY;

    auto LOADA = [&](int Inew) {
        ib = Inew * 128;
#pragma unroll
        for (int ti = 0; ti < 4; ++ti) {
            const __hip_bfloat16* ap = fb + (size_t)(ib + wi * 64 + ti * 16 + l15) * C + quad * 8;
#pragma unroll
            for (int k = 0; k < 8; ++k)
                a[ti][k] = *(const short8*)(ap + k * 32);
#pragma unroll
            for (int r = 0; r < 4; ++r)
                si[ti][r] = sq[ib + wi * 64 + ti * 16 + quad * 4 + r];
        }
    };

    auto FLUSH = [&]() {   // emit row-side mining state for current A rows, reset
#pragma unroll
        for (int ti = 0; ti < 4; ++ti)
#pragma unroll
        for (int r = 0; r < 4; ++r) {
            float v = nm[ti][r];
#pragma unroll
            for (int off = 1; off < 16; off <<= 1) v = fminf(v, __shfl_xor(v, off));
            if (l15 == 0) {
                int row = ib + wi * 64 + ti * 16 + quad * 4 + r;
                float d2 = fmaxf(v + sq[row], 0.f);
                atomicMin(&negmin[row], __float_as_uint(d2));
            }
            nm[ti][r] = INFINITY;
        }
        if ((l15 >> 2) == quad) {
#pragma unroll
            for (int s2 = 0; s2 < 2; ++s2) {
                int row = ib + wi * 64 + (wj * 2 + s2) * 16 + l15;
                float d2 = fmaxf(pm[s2] + sq[row], 0.f);
                atomicMax(&posmax[row], __float_as_uint(d2));
            }
        }
        pm[0] = -INFINITY; pm[1] = -INFINITY;
    };

    auto STAGE = [&](int jb, int cb) {   // stage 64 rows x 256 K into Bs[cb]
        const __hip_bfloat16* src = fb + (size_t)jb * C;
        uint4* d = &Bs[cb][0] + (t & ~63);
#pragma unroll
        for (int it = 0; it < 8; ++it)
            async16(src + soff[it], d + it * 256);
    };

    auto COMPUTE = [&](int jb, int cb, int sub, bool self) {
        float sj0 = sq[jb + wj * 32 + l15];
        float sj1 = sq[jb + wj * 32 + 16 + l15];

        floatx4 acc[4][2];
#pragma unroll
        for (int ti = 0; ti < 4; ++ti)
#pragma unroll
            for (int tjj = 0; tjj < 2; ++tjj)
                acc[ti][tjj] = (floatx4){0.f, 0.f, 0.f, 0.f};

        __builtin_amdgcn_s_setprio(1);
#pragma unroll
        for (int k = 0; k < 8; ++k) {
            short8 b[2];
#pragma unroll
            for (int tjj = 0; tjj < 2; ++tjj) {
                int col = wj * 32 + tjj * 16 + l15;
                int g = (k * 4 + quad) ^ (col & 7);
                b[tjj] = *(const short8*)&Bs[cb][col * 32 + g];
            }
#pragma unroll
            for (int ti = 0; ti < 4; ++ti)
#pragma unroll
                for (int tjj = 0; tjj < 2; ++tjj)
                    acc[ti][tjj] = __builtin_amdgcn_mfma_f32_16x16x32_bf16(
                        a[ti][k], b[tjj], acc[ti][tjj], 0, 0, 0);
        }
        __builtin_amdgcn_s_setprio(0);

        // ---- dual mining epilogue ----
        float cml[2] = {INFINITY, INFINITY};
#pragma unroll
        for (int tjj = 0; tjj < 2; ++tjj) {
            float sj = tjj ? sj1 : sj0;
            int cband = sub * 4 + wj * 2 + tjj;     // col band-of-16 within 128-tile
#pragma unroll
            for (int ti = 0; ti < 4; ++ti) {
                bool dtile = (wi * 4 + ti) == cband;  // wave-uniform
#pragma unroll
                for (int r = 0; r < 4; ++r) {
                    float dot = acc[ti][tjj][r];
                    float v = fmaf(-2.f, dot, sj);          // row view
                    if (self) {
                        bool isd = dtile && (l15 == quad * 4 + r);   // j == i
                        nm[ti][r] = fminf(nm[ti][r], isd ? INFINITY : v);
                    } else {
                        float wv = fmaf(-2.f, dot, si[ti][r]);       // col view
                        if (dtile) {
                            bool isd = (l15 == quad * 4 + r);        // same label
                            nm[ti][r] = fminf(nm[ti][r], isd ? INFINITY : v);
                            cml[tjj] = fminf(cml[tjj], isd ? INFINITY : wv);
                            pm[tjj] = fmaxf(pm[tjj], isd ? v : -INFINITY);
                            if (isd) {                               // col-side positive
                                float d2c = fmaxf(wv + sj, 0.f);
                                atomicMax(&posmax[jb + wj * 32 + tjj * 16 + l15],
                                          __float_as_uint(d2c));
                            }
                        } else {
                            nm[ti][r] = fminf(nm[ti][r], v);
                            cml[tjj] = fminf(cml[tjj], wv);
                        }
                    }
                }
            }
        }
        if (!self) {   // col-mining flush: min over this wave's 64 rows -> atomic
#pragma unroll
            for (int tjj = 0; tjj < 2; ++tjj) {
                float c2 = cml[tjj];
                c2 = fminf(c2, __shfl_xor(c2, 16));
                c2 = fminf(c2, __shfl_xor(c2, 32));
                if (quad == 0) {
                    float sj = tjj ? sj1 : sj0;
                    float d2 = fmaxf(c2 + sj, 0.f);
                    atomicMin(&negmin[jb + wj * 32 + tjj * 16 + l15],
                              __float_as_uint(d2));
                }
            }
        }
    };

    // ---- pipelined main loop: 2 phases per tile, double-buffered LDS ----
    LOADA(I);
    STAGE(J * 128, 0);
    __syncthreads();
#pragma unroll 1
    for (;;) {
        const bool lastTile = (tt + 1 >= tend);
        const int strip_end = base + 64 - I;
        int In = I, Jn = J + 1, nbase = base;
        if (tt + 1 == strip_end) { nbase = strip_end; In = I + 1; Jn = In; }
        const bool self = (I == J);
        const int jb = J * 128;

        STAGE(jb + 64, 1);                  // sub1 of current tile -> Bs[1]
        COMPUTE(jb, 0, 0, self);            // sub0 from Bs[0]
        __syncthreads();                    // Bs[1] staged; Bs[0] reads done
        if (!lastTile) STAGE(Jn * 128, 0);  // sub0 of next tile -> Bs[0]
        COMPUTE(jb + 64, 1, 1, self);       // sub1 from Bs[1]
        __syncthreads();                    // Bs[0] staged; Bs[1] reads done
        if (lastTile) break;
        if (In != I) { FLUSH(); LOADA(In); }
        I = In; J = Jn; base = nbase; ++tt;
    }
    FLUSH();

    // ---- last-block finalize (replaces k_final launch) ----
    __threadfence();
    __syncthreads();
    if (t == 0) sTicket = atomicAdd(done, 1u);
    __syncthreads();
    if (sTicket == 511u) {
        __threadfence();
        float acc = 0.f;
        for (int i = t; i < N; i += 256) {
            unsigned pu = __hip_atomic_load(&posmax[i], __ATOMIC_RELAXED, __HIP_MEMORY_SCOPE_AGENT);
            unsigned nu = __hip_atomic_load(&negmin[i], __ATOMIC_RELAXED, __HIP_MEMORY_SCOPE_AGENT);
            float hp = sqrtf(__uint_as_float(pu));
            float hn = sqrtf(__uint_as_float(nu));
            acc += fmaxf(hp - hn + MARGIN, 0.f);
        }
#pragma unroll
        for (int off = 32; off; off >>= 1) acc += __shfl_xor(acc, off);
        if (lane == 0) fred[w] = acc;
        __syncthreads();
        if (t == 0) {
            float tsum = fred[0] + fred[1] + fred[2] + fred[3];
            float ssum = 0.f;
            for (int i = 0; i < 64; ++i)
                ssum += __hip_atomic_load((float*)&scalars[1 + i], __ATOMIC_RELAXED,
                                          __HIP_MEMORY_SCOPE_AGENT);
            out[0] = ssum + tsum * (1.f / N);
        }
    }
}

extern "C" void kernel_launch(void* const* d_in, const int* in_sizes, int n_in,
                              void* d_out, int out_size, void* d_ws, size_t ws_size,
                              hipStream_t stream) {
    const float* feat = (const float*)d_in[0];
    const float* gt   = (const float*)d_in[1];
    const float* s0   = (const float*)d_in[2];
    const float* s1   = (const float*)d_in[3];
    const float* s2   = (const float*)d_in[4];
    const float* e0   = (const float*)d_in[5];
    const float* e1   = (const float*)d_in[6];
    const float* l0   = (const float*)d_in[7];
    const float* l1   = (const float*)d_in[8];
    float* out = (float*)d_out;

    char* ws = (char*)d_ws;
    __hip_bfloat16* fb = (__hip_bfloat16*)ws;                       // 4 MB
    float*    sq      = (float*)(ws + (size_t)N * C * 2);
    unsigned* posmax  = (unsigned*)(ws + (size_t)N * C * 2 + N * 4);
    unsigned* negmin  = (unsigned*)(ws + (size_t)N * C * 2 + N * 8);
    float*    scalars = (float*)(ws + (size_t)N * C * 2 + N * 12);  // 65 floats
    unsigned* done    = (unsigned*)(scalars + 72);

    k_prep_sq<<<N / 4 + 64, 256, 0, stream>>>(feat, fb, sq, posmax, negmin,
                                              s0, s1, s2, gt, e0, e1, l0, l1,
                                              scalars, done);
    k_trip<<<512, 256, 0, stream>>>(fb, sq, posmax, negmin, scalars, done, out);
}